// Round 10
// baseline (1238.376 us; speedup 1.0000x reference)
//
#include <hip/hip_runtime.h>
#include <math.h>

#define N_NODES 20000
#define N_EDGES 320000
#define N_GRAPHS 128
#define L 8
#define NB0 8   // k_lin0 batching (unchanged)
#define NBC 4   // k_conv / k_mlp2 batching (halved: 2x waves, half critical path)
#define EPS_BN 1e-5f
#define EPS_MSG 1e-7f
#define EPS_SM 1e-16f
#define SLOPE 0.01f

__device__ __forceinline__ float leakyf(float x) { return x >= 0.f ? x : SLOPE * x; }

// Wave-synchronous LDS handoff: HW guarantees same-wave DS ops complete in
// order; the asm memory clobbers stop the COMPILER from moving LDS accesses
// across this point (wave_barrier alone is IntrNoMem and does not).
__device__ __forceinline__ void wave_sync_lds() {
  asm volatile("" ::: "memory");
  __builtin_amdgcn_wave_barrier();
  asm volatile("" ::: "memory");
}

// ---------------- CSR build ----------------
__global__ void k_hist(const int* __restrict__ dst, int* __restrict__ counts) {
  int i = blockIdx.x * blockDim.x + threadIdx.x;
  if (i < N_EDGES) atomicAdd(&counts[dst[i]], 1);
}

// 3-phase scan: 1024 threads, each owns a contiguous chunk.
__global__ __launch_bounds__(1024) void k_scan(const int* __restrict__ counts,
                                               int* __restrict__ row_ptr,
                                               int* __restrict__ cursor, int n) {
  __shared__ int psum[16];
  int tid = threadIdx.x;
  const int CHUNK = (n + 1023) / 1024;
  int start = tid * CHUNK;
  int end = start + CHUNK; if (end > n) end = n;
  int s = 0;
  for (int i = start; i < end; i++) s += counts[i];
  int lane = tid & 63, w = tid >> 6;
  int incl = s;
  for (int off = 1; off < 64; off <<= 1) {
    int u = __shfl_up(incl, off);
    if (lane >= off) incl += u;
  }
  if (lane == 63) psum[w] = incl;
  __syncthreads();
  int woff = 0;
  for (int k = 0; k < w; k++) woff += psum[k];
  int run = woff + incl - s;  // exclusive prefix of this thread's chunk
  for (int i = start; i < end; i++) {
    row_ptr[i] = run; cursor[i] = run; run += counts[i];
  }
  if (tid == 1023) row_ptr[n] = run;
}

// Packed edge record: .x = source node id, .y = edge_attr bits (float).
__global__ void k_scatter(const int* __restrict__ src, const int* __restrict__ dst,
                          const float* __restrict__ eattr, int* __restrict__ cursor,
                          int2* __restrict__ edata, int e) {
  int i = blockIdx.x * blockDim.x + threadIdx.x;
  if (i < e) {
    int d = dst[i];
    int pos = atomicAdd(&cursor[d], 1);
    edata[pos] = make_int2(src[i], __float_as_int(eattr[i]));
  }
}

// ---------------- layer-0 projections: xs0 = x@Wsrc+bsrc, xd0 = x@Wdst+bdst ----------------
__global__ __launch_bounds__(256) void k_lin0(const float* __restrict__ x,
                                              const float* __restrict__ Wsrc, const float* __restrict__ bsrc,
                                              const float* __restrict__ Wdst, const float* __restrict__ bdst,
                                              float* __restrict__ xs0, float* __restrict__ xd0) {
  __shared__ alignas(16) float xsh[4][NB0][128];
  int tid = threadIdx.x, lane = tid & 63, w = tid >> 6;
  int l5 = lane & 31, jh = lane >> 5;
  int c2 = l5 * 2;
  float bs0 = bsrc[c2], bs1 = bsrc[c2 + 1], bd0 = bdst[c2], bd1 = bdst[c2 + 1];
  float as0[NB0], as1[NB0], ad0[NB0], ad1[NB0];
  int wave = blockIdx.x * 4 + w, nw = gridDim.x * 4;
  const int NBATCH = N_NODES / NB0;
  for (int b = wave; b < NBATCH; b += nw) {
    int n0 = b * NB0;
#pragma unroll
    for (int i = 0; i < NB0; i++) {
      float2 xv = *(const float2*)&x[(n0 + i) * 128 + lane * 2];
      *(float2*)&xsh[w][i][lane * 2] = xv;
    }
    wave_sync_lds();
#pragma unroll
    for (int i = 0; i < NB0; i++) { as0[i] = as1[i] = ad0[i] = ad1[i] = 0.f; }
    for (int j4 = 0; j4 < 16; j4++) {
      int j = jh * 64 + j4 * 4;
      float2 s0 = *(const float2*)&Wsrc[(j + 0) * 64 + c2];
      float2 s1 = *(const float2*)&Wsrc[(j + 1) * 64 + c2];
      float2 s2 = *(const float2*)&Wsrc[(j + 2) * 64 + c2];
      float2 s3 = *(const float2*)&Wsrc[(j + 3) * 64 + c2];
      float2 d0 = *(const float2*)&Wdst[(j + 0) * 64 + c2];
      float2 d1 = *(const float2*)&Wdst[(j + 1) * 64 + c2];
      float2 d2 = *(const float2*)&Wdst[(j + 2) * 64 + c2];
      float2 d3 = *(const float2*)&Wdst[(j + 3) * 64 + c2];
#pragma unroll
      for (int i = 0; i < NB0; i++) {
        float4 o = *(const float4*)&xsh[w][i][j];
        as0[i] = fmaf(o.x, s0.x, as0[i]); as1[i] = fmaf(o.x, s0.y, as1[i]);
        ad0[i] = fmaf(o.x, d0.x, ad0[i]); ad1[i] = fmaf(o.x, d0.y, ad1[i]);
        as0[i] = fmaf(o.y, s1.x, as0[i]); as1[i] = fmaf(o.y, s1.y, as1[i]);
        ad0[i] = fmaf(o.y, d1.x, ad0[i]); ad1[i] = fmaf(o.y, d1.y, ad1[i]);
        as0[i] = fmaf(o.z, s2.x, as0[i]); as1[i] = fmaf(o.z, s2.y, as1[i]);
        ad0[i] = fmaf(o.z, d2.x, ad0[i]); ad1[i] = fmaf(o.z, d2.y, ad1[i]);
        as0[i] = fmaf(o.w, s3.x, as0[i]); as1[i] = fmaf(o.w, s3.y, as1[i]);
        ad0[i] = fmaf(o.w, d3.x, ad0[i]); ad1[i] = fmaf(o.w, d3.y, ad1[i]);
      }
    }
#pragma unroll
    for (int i = 0; i < NB0; i++) {
      as0[i] += __shfl_xor(as0[i], 32); as1[i] += __shfl_xor(as1[i], 32);
      ad0[i] += __shfl_xor(ad0[i], 32); ad1[i] += __shfl_xor(ad1[i], 32);
    }
#pragma unroll
    for (int u = 0; u < 4; u++) {
      int i = jh * 4 + u;
      int n = n0 + i;
      *(float2*)&xs0[n * 64 + c2] = make_float2(as0[i] + bs0, as1[i] + bs1);
      *(float2*)&xd0[n * 64 + c2] = make_float2(ad0[i] + bd0, ad1[i] + bd1);
    }
  }
}

// ---------------- conv: fused BN+leaky gather, no-max segment softmax, fused MLP-1 ----------------
// NBC=4 nodes per wave. Edge phase: stage 64 edge records with ONE coalesced
// lane-parallel load, broadcast via __shfl (bpermute) -> the only memory op in
// the inner loop is the tbl_s gather itself (pipelines 8-deep).
__global__ __launch_bounds__(256) void k_conv(
    const float* __restrict__ tbl_s, const float* __restrict__ tbl_d,
    const float* __restrict__ nstats, const float* __restrict__ ng,
    const float* __restrict__ nbv, int use_bn,
    const int* __restrict__ row_ptr, const int2* __restrict__ edata,
    const float* __restrict__ We, const float* __restrict__ be,
    const float* __restrict__ tptr,
    const float* __restrict__ W1, float* __restrict__ y1,
    float* __restrict__ stats /* [256]: sum[128], sq[128] */) {
  __shared__ alignas(16) float W1s[64 * 128];    // 32 KB (amortized over 4 batches/block)
  __shared__ alignas(16) float outs[4][NBC][64]; // 4 KB
  __shared__ float rsum[128], rsq[128];
  int tid = threadIdx.x, lane = tid & 63, w = tid >> 6;
  for (int i = tid; i < 64 * 128 / 4; i += 256)
    ((float4*)W1s)[i] = ((const float4*)W1)[i];
  if (tid < 128) { rsum[tid] = 0.f; rsq[tid] = 0.f; }
  __syncthreads();
  float sc = 1.f, sh = 0.f, slope = 1.f;
  if (use_bn) {
    const float inv = 1.f / N_NODES;
    float mu = nstats[lane] * inv;
    float var = nstats[64 + lane] * inv - mu * mu;
    sc = ng[lane] / sqrtf(var + EPS_BN);
    sh = nbv[lane] - mu * sc;
    slope = SLOPE;
  }
  float wec = We[lane], bec = be[lane], tval = tptr[0];
  int l5 = lane & 31, jh = lane >> 5;
  int c4 = l5 * 4;
  float acc[NBC][4];
  float sA[4] = {0.f, 0.f, 0.f, 0.f}, qA[4] = {0.f, 0.f, 0.f, 0.f};
  int wave = blockIdx.x * 4 + w, nw = gridDim.x * 4;
  const int NBATCH = N_NODES / NBC;
  for (int b = wave; b < NBATCH; b += nw) {
    int n0 = b * NBC;
    // ---- edge phase: one node at a time, lane = channel ----
    for (int i = 0; i < NBC; i++) {
      int n = n0 + i;
      int kb = row_ptr[n], ke = row_ptr[n + 1];
      float dtv = tbl_d[n * 64 + lane];   // issue early, used after edge loop
      float ssum = 0.f, wacc = 0.f;
      for (int k0 = kb; k0 < ke; k0 += 64) {
        int idx = k0 + lane; if (idx >= ke) idx = ke - 1;
        int2 my = edata[idx];             // one coalesced load per 64 edges
        int cnt = ke - k0; if (cnt > 64) cnt = 64;
#pragma unroll 8
        for (int j = 0; j < cnt; j++) {
          int sid = __shfl(my.x, j);      // lane-broadcast, no memory op
          float av = __int_as_float(__shfl(my.y, j));
          float hv = tbl_s[sid * 64 + lane];
          float zt = fmaf(hv, sc, sh);
          float zv = zt >= 0.f ? zt : zt * slope;
          float msg = fmaxf(zv + fmaf(av, wec, bec), 0.f) + EPS_MSG;
          float e = __expf(fminf(msg * tval, 60.f));
          ssum += e;
          wacc = fmaf(msg, e, wacc);
        }
      }
      float dt = fmaf(dtv, sc, sh);
      float dv = dt >= 0.f ? dt : dt * slope;
      outs[w][i][lane] = wacc / (ssum + EPS_SM) + dv;
    }
    wave_sync_lds();
    // ---- GEMM phase: y1[n][c] = sum_j out[n][j] * W1[j][c], W1 from LDS ----
#pragma unroll
    for (int i = 0; i < NBC; i++)
#pragma unroll
      for (int c = 0; c < 4; c++) acc[i][c] = 0.f;
    for (int j4 = 0; j4 < 8; j4++) {
      int j = jh * 32 + j4 * 4;
      float4 w0 = *(const float4*)&W1s[(j + 0) * 128 + c4];
      float4 w1 = *(const float4*)&W1s[(j + 1) * 128 + c4];
      float4 w2 = *(const float4*)&W1s[(j + 2) * 128 + c4];
      float4 w3 = *(const float4*)&W1s[(j + 3) * 128 + c4];
#pragma unroll
      for (int i = 0; i < NBC; i++) {
        float4 o = *(const float4*)&outs[w][i][j];
        acc[i][0] = fmaf(o.x, w0.x, acc[i][0]); acc[i][1] = fmaf(o.x, w0.y, acc[i][1]);
        acc[i][2] = fmaf(o.x, w0.z, acc[i][2]); acc[i][3] = fmaf(o.x, w0.w, acc[i][3]);
        acc[i][0] = fmaf(o.y, w1.x, acc[i][0]); acc[i][1] = fmaf(o.y, w1.y, acc[i][1]);
        acc[i][2] = fmaf(o.y, w1.z, acc[i][2]); acc[i][3] = fmaf(o.y, w1.w, acc[i][3]);
        acc[i][0] = fmaf(o.z, w2.x, acc[i][0]); acc[i][1] = fmaf(o.z, w2.y, acc[i][1]);
        acc[i][2] = fmaf(o.z, w2.z, acc[i][2]); acc[i][3] = fmaf(o.z, w2.w, acc[i][3]);
        acc[i][0] = fmaf(o.w, w3.x, acc[i][0]); acc[i][1] = fmaf(o.w, w3.y, acc[i][1]);
        acc[i][2] = fmaf(o.w, w3.z, acc[i][2]); acc[i][3] = fmaf(o.w, w3.w, acc[i][3]);
      }
    }
#pragma unroll
    for (int i = 0; i < NBC; i++)
#pragma unroll
      for (int c = 0; c < 4; c++) acc[i][c] += __shfl_xor(acc[i][c], 32);
    // each j-half group writes 2 nodes (full rows, coalesced float4)
#pragma unroll
    for (int u = 0; u < 2; u++) {
      int i = jh * 2 + u;
      int n = n0 + i;
      float4 v = make_float4(acc[i][0], acc[i][1], acc[i][2], acc[i][3]);
      *(float4*)&y1[n * 128 + c4] = v;
      sA[0] += v.x; qA[0] += v.x * v.x;
      sA[1] += v.y; qA[1] += v.y * v.y;
      sA[2] += v.z; qA[2] += v.z * v.z;
      sA[3] += v.w; qA[3] += v.w * v.w;
    }
  }
#pragma unroll
  for (int c = 0; c < 4; c++) {
    atomicAdd(&rsum[c4 + c], sA[c]);
    atomicAdd(&rsq[c4 + c], qA[c]);
  }
  __syncthreads();
  if (tid < 128) {
    atomicAdd(&stats[tid], rsum[tid]);
    atomicAdd(&stats[128 + tid], rsq[tid]);
  }
}

// ---------------- mlp2: h1 = relu(BN(y1)); h (+)= h1@W2 + b2; accumulate h stats ----------------
// W2 NOT staged in LDS (L2-hot at 32 KB): LDS 8.7 KB -> wave-cap residency (~8 blocks/CU).
__global__ __launch_bounds__(256) void k_mlp2(
    const float* __restrict__ y1, const float* __restrict__ ystats,
    const float* __restrict__ bng, const float* __restrict__ bnb,
    const float* __restrict__ W2, const float* __restrict__ b2,
    float* __restrict__ h, int add_res,
    float* __restrict__ hstats /* [128]: sum[64], sq[64] */) {
  __shared__ alignas(16) float h1s[4][NBC][128]; // 8 KB
  __shared__ float rsum[64], rsq[64];
  int tid = threadIdx.x, lane = tid & 63, w = tid >> 6;
  if (tid < 64) { rsum[tid] = 0.f; rsq[tid] = 0.f; }
  __syncthreads();
  const float inv = 1.f / N_NODES;
  float mua = ystats[lane] * inv, mub = ystats[64 + lane] * inv;
  float va = ystats[128 + lane] * inv - mua * mua;
  float vb = ystats[192 + lane] * inv - mub * mub;
  float sca = bng[lane] / sqrtf(va + EPS_BN), scb = bng[64 + lane] / sqrtf(vb + EPS_BN);
  float sha = bnb[lane] - mua * sca, shb = bnb[64 + lane] - mub * scb;
  int l5 = lane & 31, jh = lane >> 5;
  int c2 = l5 * 2;
  float bias0 = b2[c2], bias1 = b2[c2 + 1];
  float acc0[NBC], acc1[NBC];
  float s0 = 0.f, q0 = 0.f, s1 = 0.f, q1 = 0.f;
  int wave = blockIdx.x * 4 + w, nw = gridDim.x * 4;
  const int NBATCH = N_NODES / NBC;
  for (int b = wave; b < NBATCH; b += nw) {
    int n0 = b * NBC;
#pragma unroll
    for (int i = 0; i < NBC; i++) {
      int n = n0 + i;
      float va_ = y1[n * 128 + lane];
      float vb_ = y1[n * 128 + 64 + lane];
      h1s[w][i][lane] = fmaxf(fmaf(va_, sca, sha), 0.f);
      h1s[w][i][64 + lane] = fmaxf(fmaf(vb_, scb, shb), 0.f);
    }
    wave_sync_lds();
#pragma unroll
    for (int i = 0; i < NBC; i++) { acc0[i] = 0.f; acc1[i] = 0.f; }
    for (int j4 = 0; j4 < 16; j4++) {
      int j = jh * 64 + j4 * 4;
      float2 w0 = *(const float2*)&W2[(j + 0) * 64 + c2];
      float2 w1 = *(const float2*)&W2[(j + 1) * 64 + c2];
      float2 w2v = *(const float2*)&W2[(j + 2) * 64 + c2];
      float2 w3 = *(const float2*)&W2[(j + 3) * 64 + c2];
#pragma unroll
      for (int i = 0; i < NBC; i++) {
        float4 o = *(const float4*)&h1s[w][i][j];
        acc0[i] = fmaf(o.x, w0.x, acc0[i]); acc1[i] = fmaf(o.x, w0.y, acc1[i]);
        acc0[i] = fmaf(o.y, w1.x, acc0[i]); acc1[i] = fmaf(o.y, w1.y, acc1[i]);
        acc0[i] = fmaf(o.z, w2v.x, acc0[i]); acc1[i] = fmaf(o.z, w2v.y, acc1[i]);
        acc0[i] = fmaf(o.w, w3.x, acc0[i]); acc1[i] = fmaf(o.w, w3.y, acc1[i]);
      }
    }
#pragma unroll
    for (int i = 0; i < NBC; i++) {
      acc0[i] += __shfl_xor(acc0[i], 32);
      acc1[i] += __shfl_xor(acc1[i], 32);
    }
#pragma unroll
    for (int u = 0; u < 2; u++) {
      int i = jh * 2 + u;
      int n = n0 + i;
      float v0 = acc0[i] + bias0, v1 = acc1[i] + bias1;
      if (add_res) {
        float2 ho = *(const float2*)&h[n * 64 + c2];
        v0 += ho.x; v1 += ho.y;
      }
      *(float2*)&h[n * 64 + c2] = make_float2(v0, v1);
      s0 += v0; q0 += v0 * v0;
      s1 += v1; q1 += v1 * v1;
    }
  }
  atomicAdd(&rsum[c2], s0); atomicAdd(&rsq[c2], q0);
  atomicAdd(&rsum[c2 + 1], s1); atomicAdd(&rsq[c2 + 1], q1);
  __syncthreads();
  if (tid < 64) {
    atomicAdd(&hstats[tid], rsum[tid]);
    atomicAdd(&hstats[64 + tid], rsq[tid]);
  }
}

// ---------------- final: leaky(BN(h, norm[0])) then mean-pool; one block per graph ----------------
__device__ __forceinline__ int lower_bound_i(const int* __restrict__ b, int n, int v) {
  int lo = 0, hi = n;
  while (lo < hi) { int mid = (lo + hi) >> 1; if (b[mid] < v) lo = mid + 1; else hi = mid; }
  return lo;
}

__global__ __launch_bounds__(256) void k_pool(const float* __restrict__ h,
                                              const float* __restrict__ hstats,
                                              const float* __restrict__ g0, const float* __restrict__ b0,
                                              const int* __restrict__ batch, float* __restrict__ out) {
  __shared__ float red[4][64];
  int g = blockIdx.x;
  int tid = threadIdx.x, lane = tid & 63, w = tid >> 6;
  int start = lower_bound_i(batch, N_NODES, g);
  int end = lower_bound_i(batch, N_NODES, g + 1);
  const float inv = 1.0f / N_NODES;
  float mu = hstats[lane] * inv;
  float var = hstats[64 + lane] * inv - mu * mu;
  float sc = g0[lane] / sqrtf(var + EPS_BN);
  float sh = b0[lane] - mu * sc;
  float acc = 0.f;
  for (int n = start + w; n < end; n += 4)
    acc += leakyf(fmaf(h[n * 64 + lane], sc, sh));
  red[w][lane] = acc;
  __syncthreads();
  if (w == 0) {
    float tot = red[0][lane] + red[1][lane] + red[2][lane] + red[3][lane];
    out[g * 64 + lane] = tot / fmaxf((float)(end - start), 1.0f);
  }
}

extern "C" void kernel_launch(void* const* d_in, const int* in_sizes, int n_in,
                              void* d_out, int out_size, void* d_ws, size_t ws_size,
                              hipStream_t stream) {
  const float* x      = (const float*)d_in[0];
  const int*   eidx   = (const int*)d_in[1];
  const int*   batch  = (const int*)d_in[2];
  const float* eattr  = (const float*)d_in[3];
  const float* Wsrc   = (const float*)d_in[4];
  const float* bsrc   = (const float*)d_in[5];
  const float* Wdst   = (const float*)d_in[6];
  const float* bdst   = (const float*)d_in[7];
  const float* Wedge  = (const float*)d_in[8];
  const float* bedge  = (const float*)d_in[9];
  const float* tparam = (const float*)d_in[10];
  const float* W1     = (const float*)d_in[11];
  // d_in[12] = mlp_bias1 — cancels inside the following BatchNorm; skipped.
  const float* bng    = (const float*)d_in[13];
  const float* bnb    = (const float*)d_in[14];
  const float* W2     = (const float*)d_in[15];
  const float* b2     = (const float*)d_in[16];
  const float* ng     = (const float*)d_in[17];
  const float* nb     = (const float*)d_in[18];
  const int* srcp = eidx;              // edge_index[0]
  const int* dstp = eidx + N_EDGES;    // edge_index[1]

  char* ws = (char*)d_ws;
  size_t off = 0;
  auto alloc = [&](size_t bytes) {
    void* p = ws + off;
    off = (off + bytes + 255) & ~size_t(255);
    return p;
  };
  // ---- zero region (one memset) ----
  int*   counts   = (int*)alloc(N_NODES * 4);
  float* stats_y1 = (float*)alloc(L * 256 * 4);
  float* stats_h  = (float*)alloc(L * 128 * 4);
  size_t zero_bytes = off;
  // ---- rest ----
  int*   row_ptr    = (int*)alloc((N_NODES + 1) * 4);
  int*   cursor     = (int*)alloc(N_NODES * 4);
  int2*  edata      = (int2*)alloc(N_EDGES * 8);
  float* xs0        = (float*)alloc(N_NODES * 64 * 4);
  float* xd0        = (float*)alloc(N_NODES * 64 * 4);
  float* hbuf       = (float*)alloc(N_NODES * 64 * 4);
  float* y1         = (float*)alloc(N_NODES * 128 * 4);

  hipMemsetAsync(d_ws, 0, zero_bytes, stream);
  k_hist<<<(N_EDGES + 255) / 256, 256, 0, stream>>>(dstp, counts);
  k_scan<<<1, 1024, 0, stream>>>(counts, row_ptr, cursor, N_NODES);
  k_scatter<<<(N_EDGES + 255) / 256, 256, 0, stream>>>(srcp, dstp, eattr, cursor,
                                                       edata, N_EDGES);
  k_lin0<<<625, 256, 0, stream>>>(x, Wsrc, bsrc, Wdst, bdst, xs0, xd0);

  for (int i = 0; i < L; i++) {
    const float* xsp = (i == 0) ? xs0 : hbuf;
    const float* xdp = (i == 0) ? xd0 : hbuf;
    const float* nst = (i == 0) ? stats_h : stats_h + (i - 1) * 128;  // unused when use_bn=0
    k_conv<<<1250, 256, 0, stream>>>(xsp, xdp, nst, ng + i * 64, nb + i * 64, i > 0 ? 1 : 0,
                                     row_ptr, edata,
                                     Wedge + i * 64, bedge + i * 64, tparam + i,
                                     W1 + i * 64 * 128, y1, stats_y1 + i * 256);
    k_mlp2<<<1250, 256, 0, stream>>>(y1, stats_y1 + i * 256, bng + i * 128, bnb + i * 128,
                                     W2 + i * 128 * 64, b2 + i * 64, hbuf, i > 0 ? 1 : 0,
                                     stats_h + i * 128);
  }
  k_pool<<<N_GRAPHS, 256, 0, stream>>>(hbuf, stats_h + 7 * 128, ng, nb, batch, (float*)d_out);
}

// Round 12
// 942.040 us; speedup vs baseline: 1.3146x; 1.3146x over previous
//
#include <hip/hip_runtime.h>
#include <math.h>

#define N_NODES 20000
#define N_EDGES 320000
#define N_GRAPHS 128
#define L 8
#define NB0 8   // k_lin0 batching
#define NBC 4   // k_conv / k_mlp2 batching
#define EPS_BN 1e-5f
#define EPS_MSG 1e-7f
#define EPS_SM 1e-16f
#define SLOPE 0.01f

__device__ __forceinline__ float leakyf(float x) { return x >= 0.f ? x : SLOPE * x; }

// Wave-synchronous LDS handoff (compiler fence + wave barrier).
__device__ __forceinline__ void wave_sync_lds() {
  asm volatile("" ::: "memory");
  __builtin_amdgcn_wave_barrier();
  asm volatile("" ::: "memory");
}

// ---------------- CSR build ----------------
__global__ void k_hist(const int* __restrict__ dst, int* __restrict__ counts) {
  int i = blockIdx.x * blockDim.x + threadIdx.x;
  if (i < N_EDGES) atomicAdd(&counts[dst[i]], 1);
}

__global__ __launch_bounds__(1024) void k_scan(const int* __restrict__ counts,
                                               int* __restrict__ row_ptr,
                                               int* __restrict__ cursor, int n) {
  __shared__ int psum[16];
  int tid = threadIdx.x;
  const int CHUNK = (n + 1023) / 1024;
  int start = tid * CHUNK;
  int end = start + CHUNK; if (end > n) end = n;
  int s = 0;
  for (int i = start; i < end; i++) s += counts[i];
  int lane = tid & 63, w = tid >> 6;
  int incl = s;
  for (int off = 1; off < 64; off <<= 1) {
    int u = __shfl_up(incl, off);
    if (lane >= off) incl += u;
  }
  if (lane == 63) psum[w] = incl;
  __syncthreads();
  int woff = 0;
  for (int k = 0; k < w; k++) woff += psum[k];
  int run = woff + incl - s;
  for (int i = start; i < end; i++) {
    row_ptr[i] = run; cursor[i] = run; run += counts[i];
  }
  if (tid == 1023) row_ptr[n] = run;
}

// Packed edge record: .x = source node id, .y = edge_attr bits (float).
__global__ void k_scatter(const int* __restrict__ src, const int* __restrict__ dst,
                          const float* __restrict__ eattr, int* __restrict__ cursor,
                          int2* __restrict__ edata, int e) {
  int i = blockIdx.x * blockDim.x + threadIdx.x;
  if (i < e) {
    int d = dst[i];
    int pos = atomicAdd(&cursor[d], 1);
    edata[pos] = make_int2(src[i], __float_as_int(eattr[i]));
  }
}

// ---------------- layer-0 projections ----------------
__global__ __launch_bounds__(256) void k_lin0(const float* __restrict__ x,
                                              const float* __restrict__ Wsrc, const float* __restrict__ bsrc,
                                              const float* __restrict__ Wdst, const float* __restrict__ bdst,
                                              float* __restrict__ xs0, float* __restrict__ xd0) {
  __shared__ alignas(16) float xsh[4][NB0][128];
  int tid = threadIdx.x, lane = tid & 63, w = tid >> 6;
  int l5 = lane & 31, jh = lane >> 5;
  int c2 = l5 * 2;
  float bs0 = bsrc[c2], bs1 = bsrc[c2 + 1], bd0 = bdst[c2], bd1 = bdst[c2 + 1];
  float as0[NB0], as1[NB0], ad0[NB0], ad1[NB0];
  int wave = blockIdx.x * 4 + w, nw = gridDim.x * 4;
  const int NBATCH = N_NODES / NB0;
  for (int b = wave; b < NBATCH; b += nw) {
    int n0 = b * NB0;
    // batched staging: issue all 8 loads, then write LDS
    float2 xv[NB0];
#pragma unroll
    for (int i = 0; i < NB0; i++)
      xv[i] = *(const float2*)&x[(n0 + i) * 128 + lane * 2];
#pragma unroll
    for (int i = 0; i < NB0; i++)
      *(float2*)&xsh[w][i][lane * 2] = xv[i];
    wave_sync_lds();
#pragma unroll
    for (int i = 0; i < NB0; i++) { as0[i] = as1[i] = ad0[i] = ad1[i] = 0.f; }
    for (int j4 = 0; j4 < 16; j4++) {
      int j = jh * 64 + j4 * 4;
      float2 s0 = *(const float2*)&Wsrc[(j + 0) * 64 + c2];
      float2 s1 = *(const float2*)&Wsrc[(j + 1) * 64 + c2];
      float2 s2 = *(const float2*)&Wsrc[(j + 2) * 64 + c2];
      float2 s3 = *(const float2*)&Wsrc[(j + 3) * 64 + c2];
      float2 d0 = *(const float2*)&Wdst[(j + 0) * 64 + c2];
      float2 d1 = *(const float2*)&Wdst[(j + 1) * 64 + c2];
      float2 d2 = *(const float2*)&Wdst[(j + 2) * 64 + c2];
      float2 d3 = *(const float2*)&Wdst[(j + 3) * 64 + c2];
#pragma unroll
      for (int i = 0; i < NB0; i++) {
        float4 o = *(const float4*)&xsh[w][i][j];
        as0[i] = fmaf(o.x, s0.x, as0[i]); as1[i] = fmaf(o.x, s0.y, as1[i]);
        ad0[i] = fmaf(o.x, d0.x, ad0[i]); ad1[i] = fmaf(o.x, d0.y, ad1[i]);
        as0[i] = fmaf(o.y, s1.x, as0[i]); as1[i] = fmaf(o.y, s1.y, as1[i]);
        ad0[i] = fmaf(o.y, d1.x, ad0[i]); ad1[i] = fmaf(o.y, d1.y, ad1[i]);
        as0[i] = fmaf(o.z, s2.x, as0[i]); as1[i] = fmaf(o.z, s2.y, as1[i]);
        ad0[i] = fmaf(o.z, d2.x, ad0[i]); ad1[i] = fmaf(o.z, d2.y, ad1[i]);
        as0[i] = fmaf(o.w, s3.x, as0[i]); as1[i] = fmaf(o.w, s3.y, as1[i]);
        ad0[i] = fmaf(o.w, d3.x, ad0[i]); ad1[i] = fmaf(o.w, d3.y, ad1[i]);
      }
    }
#pragma unroll
    for (int i = 0; i < NB0; i++) {
      as0[i] += __shfl_xor(as0[i], 32); as1[i] += __shfl_xor(as1[i], 32);
      ad0[i] += __shfl_xor(ad0[i], 32); ad1[i] += __shfl_xor(ad1[i], 32);
    }
#pragma unroll
    for (int u = 0; u < 4; u++) {
      int i = jh * 4 + u;
      int n = n0 + i;
      *(float2*)&xs0[n * 64 + c2] = make_float2(as0[i] + bs0, as1[i] + bs1);
      *(float2*)&xd0[n * 64 + c2] = make_float2(ad0[i] + bd0, ad1[i] + bd1);
    }
  }
}

// ---------------- conv: explicit 8-deep gather pipelining ----------------
__global__ __launch_bounds__(256) void k_conv(
    const float* __restrict__ tbl_s, const float* __restrict__ tbl_d,
    const float* __restrict__ nstats, const float* __restrict__ ng,
    const float* __restrict__ nbv, int use_bn,
    const int* __restrict__ row_ptr, const int2* __restrict__ edata,
    const float* __restrict__ We, const float* __restrict__ be,
    const float* __restrict__ tptr,
    const float* __restrict__ W1, float* __restrict__ y1,
    float* __restrict__ stats /* [256]: sum[128], sq[128] */) {
  __shared__ alignas(16) float W1s[64 * 128];    // 32 KB
  __shared__ alignas(16) float outs[4][NBC][64]; // 4 KB
  __shared__ float rsum[128], rsq[128];
  int tid = threadIdx.x, lane = tid & 63, w = tid >> 6;
  {
    // batched W1 stage: 8 loads in flight, then LDS writes
    float4 t[8];
#pragma unroll
    for (int i = 0; i < 8; i++) t[i] = ((const float4*)W1)[tid + i * 256];
#pragma unroll
    for (int i = 0; i < 8; i++) ((float4*)W1s)[tid + i * 256] = t[i];
  }
  if (tid < 128) { rsum[tid] = 0.f; rsq[tid] = 0.f; }
  __syncthreads();
  float sc = 1.f, sh = 0.f, slope = 1.f;
  if (use_bn) {
    const float inv = 1.f / N_NODES;
    float mu = nstats[lane] * inv;
    float var = nstats[64 + lane] * inv - mu * mu;
    sc = ng[lane] / sqrtf(var + EPS_BN);
    sh = nbv[lane] - mu * sc;
    slope = SLOPE;
  }
  float wec = We[lane], bec = be[lane], tval = tptr[0];
  int l5 = lane & 31, jh = lane >> 5;
  int c4 = l5 * 4;
  float acc[NBC][4];
  float sA[4] = {0.f, 0.f, 0.f, 0.f}, qA[4] = {0.f, 0.f, 0.f, 0.f};
  int wave = blockIdx.x * 4 + w, nw = gridDim.x * 4;
  const int NBATCH = N_NODES / NBC;
  for (int b = wave; b < NBATCH; b += nw) {
    int n0 = b * NBC;
    // ---- prefetch: edge-tile + dst-row for ALL nodes up front ----
    int kbv[NBC], kev[NBC];
#pragma unroll
    for (int i = 0; i < NBC; i++) {
      kbv[i] = row_ptr[n0 + i];
      kev[i] = row_ptr[n0 + i + 1];
    }
    int2 myv[NBC];
    float dtv[NBC];
#pragma unroll
    for (int i = 0; i < NBC; i++) {
      int idx = kbv[i] + lane;
      if (idx >= kev[i]) idx = kev[i] - 1;
      if (idx < 0) idx = 0;
      myv[i] = edata[idx];                  // NBC independent coalesced loads
      dtv[i] = tbl_d[(n0 + i) * 64 + lane]; // + NBC row loads, all in flight
    }
    // ---- edge phase: groups of 8 gathers issued before any consumption ----
    for (int i = 0; i < NBC; i++) {
      int kb = kbv[i], ke = kev[i];
      float ssum = 0.f, wacc = 0.f;
      int2 my = myv[i];
      for (int base = kb; base < ke; base += 64) {
        int cnt = ke - base; if (cnt > 64) cnt = 64;
        for (int j0 = 0; j0 < cnt; j0 += 8) {
          float hv[8], av[8];
#pragma unroll
          for (int jj = 0; jj < 8; jj++) {
            int jc = j0 + jj; if (jc >= cnt) jc = cnt - 1;  // padded duplicate load
            int sid = __shfl(my.x, jc);
            av[jj] = __int_as_float(__shfl(my.y, jc));
            hv[jj] = tbl_s[sid * 64 + lane];                // 8 loads in flight
          }
#pragma unroll
          for (int jj = 0; jj < 8; jj++) {
            float zt = fmaf(hv[jj], sc, sh);
            float zv = zt >= 0.f ? zt : zt * slope;
            float msg = fmaxf(zv + fmaf(av[jj], wec, bec), 0.f) + EPS_MSG;
            float e = (j0 + jj < cnt) ? __expf(fminf(msg * tval, 60.f)) : 0.f;
            ssum += e;
            wacc = fmaf(msg, e, wacc);
          }
        }
        if (base + 64 < ke) {
          int idx = base + 64 + lane; if (idx >= ke) idx = ke - 1;
          my = edata[idx];
        }
      }
      float dt = fmaf(dtv[i], sc, sh);
      float dv = dt >= 0.f ? dt : dt * slope;
      outs[w][i][lane] = wacc / (ssum + EPS_SM) + dv;
    }
    wave_sync_lds();
    // ---- GEMM phase: y1[n][c] = sum_j out[n][j] * W1[j][c], W1 from LDS ----
#pragma unroll
    for (int i = 0; i < NBC; i++)
#pragma unroll
      for (int c = 0; c < 4; c++) acc[i][c] = 0.f;
    for (int j4 = 0; j4 < 8; j4++) {
      int j = jh * 32 + j4 * 4;
      float4 w0 = *(const float4*)&W1s[(j + 0) * 128 + c4];
      float4 w1 = *(const float4*)&W1s[(j + 1) * 128 + c4];
      float4 w2 = *(const float4*)&W1s[(j + 2) * 128 + c4];
      float4 w3 = *(const float4*)&W1s[(j + 3) * 128 + c4];
#pragma unroll
      for (int i = 0; i < NBC; i++) {
        float4 o = *(const float4*)&outs[w][i][j];
        acc[i][0] = fmaf(o.x, w0.x, acc[i][0]); acc[i][1] = fmaf(o.x, w0.y, acc[i][1]);
        acc[i][2] = fmaf(o.x, w0.z, acc[i][2]); acc[i][3] = fmaf(o.x, w0.w, acc[i][3]);
        acc[i][0] = fmaf(o.y, w1.x, acc[i][0]); acc[i][1] = fmaf(o.y, w1.y, acc[i][1]);
        acc[i][2] = fmaf(o.y, w1.z, acc[i][2]); acc[i][3] = fmaf(o.y, w1.w, acc[i][3]);
        acc[i][0] = fmaf(o.z, w2.x, acc[i][0]); acc[i][1] = fmaf(o.z, w2.y, acc[i][1]);
        acc[i][2] = fmaf(o.z, w2.z, acc[i][2]); acc[i][3] = fmaf(o.z, w2.w, acc[i][3]);
        acc[i][0] = fmaf(o.w, w3.x, acc[i][0]); acc[i][1] = fmaf(o.w, w3.y, acc[i][1]);
        acc[i][2] = fmaf(o.w, w3.z, acc[i][2]); acc[i][3] = fmaf(o.w, w3.w, acc[i][3]);
      }
    }
#pragma unroll
    for (int i = 0; i < NBC; i++)
#pragma unroll
      for (int c = 0; c < 4; c++) acc[i][c] += __shfl_xor(acc[i][c], 32);
#pragma unroll
    for (int u = 0; u < 2; u++) {
      int i = jh * 2 + u;
      int n = n0 + i;
      float4 v = make_float4(acc[i][0], acc[i][1], acc[i][2], acc[i][3]);
      *(float4*)&y1[n * 128 + c4] = v;
      sA[0] += v.x; qA[0] += v.x * v.x;
      sA[1] += v.y; qA[1] += v.y * v.y;
      sA[2] += v.z; qA[2] += v.z * v.z;
      sA[3] += v.w; qA[3] += v.w * v.w;
    }
  }
#pragma unroll
  for (int c = 0; c < 4; c++) {
    atomicAdd(&rsum[c4 + c], sA[c]);
    atomicAdd(&rsq[c4 + c], qA[c]);
  }
  __syncthreads();
  if (tid < 128) {
    atomicAdd(&stats[tid], rsum[tid]);
    atomicAdd(&stats[128 + tid], rsq[tid]);
  }
}

// ---------------- mlp2: batched staging + LDS W2 ----------------
__global__ __launch_bounds__(256) void k_mlp2(
    const float* __restrict__ y1, const float* __restrict__ ystats,
    const float* __restrict__ bng, const float* __restrict__ bnb,
    const float* __restrict__ W2, const float* __restrict__ b2,
    float* __restrict__ h, int add_res,
    float* __restrict__ hstats /* [128]: sum[64], sq[64] */) {
  __shared__ alignas(16) float W2s[128 * 64];    // 32 KB
  __shared__ alignas(16) float h1s[4][NBC][128]; // 8 KB
  __shared__ float rsum[64], rsq[64];
  int tid = threadIdx.x, lane = tid & 63, w = tid >> 6;
  {
    float4 t[8];
#pragma unroll
    for (int i = 0; i < 8; i++) t[i] = ((const float4*)W2)[tid + i * 256];
#pragma unroll
    for (int i = 0; i < 8; i++) ((float4*)W2s)[tid + i * 256] = t[i];
  }
  if (tid < 64) { rsum[tid] = 0.f; rsq[tid] = 0.f; }
  __syncthreads();
  const float inv = 1.f / N_NODES;
  float mua = ystats[lane] * inv, mub = ystats[64 + lane] * inv;
  float va = ystats[128 + lane] * inv - mua * mua;
  float vb = ystats[192 + lane] * inv - mub * mub;
  float sca = bng[lane] / sqrtf(va + EPS_BN), scb = bng[64 + lane] / sqrtf(vb + EPS_BN);
  float sha = bnb[lane] - mua * sca, shb = bnb[64 + lane] - mub * scb;
  int l5 = lane & 31, jh = lane >> 5;
  int c2 = l5 * 2;
  float bias0 = b2[c2], bias1 = b2[c2 + 1];
  float acc0[NBC], acc1[NBC];
  float s0 = 0.f, q0 = 0.f, s1 = 0.f, q1 = 0.f;
  int wave = blockIdx.x * 4 + w, nw = gridDim.x * 4;
  const int NBATCH = N_NODES / NBC;
  for (int b = wave; b < NBATCH; b += nw) {
    int n0 = b * NBC;
    // batched y1 staging: all 8 loads in flight before any LDS write
    float ya[NBC], yb[NBC];
#pragma unroll
    for (int i = 0; i < NBC; i++) {
      ya[i] = y1[(n0 + i) * 128 + lane];
      yb[i] = y1[(n0 + i) * 128 + 64 + lane];
    }
#pragma unroll
    for (int i = 0; i < NBC; i++) {
      h1s[w][i][lane] = fmaxf(fmaf(ya[i], sca, sha), 0.f);
      h1s[w][i][64 + lane] = fmaxf(fmaf(yb[i], scb, shb), 0.f);
    }
    wave_sync_lds();
#pragma unroll
    for (int i = 0; i < NBC; i++) { acc0[i] = 0.f; acc1[i] = 0.f; }
    for (int j4 = 0; j4 < 16; j4++) {
      int j = jh * 64 + j4 * 4;
      float2 w0 = *(const float2*)&W2s[(j + 0) * 64 + c2];
      float2 w1 = *(const float2*)&W2s[(j + 1) * 64 + c2];
      float2 w2v = *(const float2*)&W2s[(j + 2) * 64 + c2];
      float2 w3 = *(const float2*)&W2s[(j + 3) * 64 + c2];
#pragma unroll
      for (int i = 0; i < NBC; i++) {
        float4 o = *(const float4*)&h1s[w][i][j];
        acc0[i] = fmaf(o.x, w0.x, acc0[i]); acc1[i] = fmaf(o.x, w0.y, acc1[i]);
        acc0[i] = fmaf(o.y, w1.x, acc0[i]); acc1[i] = fmaf(o.y, w1.y, acc1[i]);
        acc0[i] = fmaf(o.z, w2v.x, acc0[i]); acc1[i] = fmaf(o.z, w2v.y, acc1[i]);
        acc0[i] = fmaf(o.w, w3.x, acc0[i]); acc1[i] = fmaf(o.w, w3.y, acc1[i]);
      }
    }
#pragma unroll
    for (int i = 0; i < NBC; i++) {
      acc0[i] += __shfl_xor(acc0[i], 32);
      acc1[i] += __shfl_xor(acc1[i], 32);
    }
    // batched residual read, then compute+store
    int nA = n0 + jh * 2, nB = nA + 1;
    float2 hA = make_float2(0.f, 0.f), hB = make_float2(0.f, 0.f);
    if (add_res) {
      hA = *(const float2*)&h[nA * 64 + c2];
      hB = *(const float2*)&h[nB * 64 + c2];
    }
    {
      int iA = jh * 2, iB = iA + 1;
      float vA0 = acc0[iA] + bias0 + hA.x, vA1 = acc1[iA] + bias1 + hA.y;
      float vB0 = acc0[iB] + bias0 + hB.x, vB1 = acc1[iB] + bias1 + hB.y;
      *(float2*)&h[nA * 64 + c2] = make_float2(vA0, vA1);
      *(float2*)&h[nB * 64 + c2] = make_float2(vB0, vB1);
      s0 += vA0 + vB0; q0 += vA0 * vA0 + vB0 * vB0;
      s1 += vA1 + vB1; q1 += vA1 * vA1 + vB1 * vB1;
    }
  }
  atomicAdd(&rsum[c2], s0); atomicAdd(&rsq[c2], q0);
  atomicAdd(&rsum[c2 + 1], s1); atomicAdd(&rsq[c2 + 1], q1);
  __syncthreads();
  if (tid < 64) {
    atomicAdd(&hstats[tid], rsum[tid]);
    atomicAdd(&hstats[64 + tid], rsq[tid]);
  }
}

// ---------------- final: leaky(BN(h, norm[0])) then mean-pool; one block per graph ----------------
__device__ __forceinline__ int lower_bound_i(const int* __restrict__ b, int n, int v) {
  int lo = 0, hi = n;
  while (lo < hi) { int mid = (lo + hi) >> 1; if (b[mid] < v) lo = mid + 1; else hi = mid; }
  return lo;
}

__global__ __launch_bounds__(256) void k_pool(const float* __restrict__ h,
                                              const float* __restrict__ hstats,
                                              const float* __restrict__ g0, const float* __restrict__ b0,
                                              const int* __restrict__ batch, float* __restrict__ out) {
  __shared__ float red[4][64];
  int g = blockIdx.x;
  int tid = threadIdx.x, lane = tid & 63, w = tid >> 6;
  int start = lower_bound_i(batch, N_NODES, g);
  int end = lower_bound_i(batch, N_NODES, g + 1);
  const float inv = 1.0f / N_NODES;
  float mu = hstats[lane] * inv;
  float var = hstats[64 + lane] * inv - mu * mu;
  float sc = g0[lane] / sqrtf(var + EPS_BN);
  float sh = b0[lane] - mu * sc;
  float acc = 0.f;
  int n = start + w;
  for (; n + 12 < end; n += 16) {        // 4 loads in flight per iteration
    float a0 = h[n * 64 + lane];
    float a1 = h[(n + 4) * 64 + lane];
    float a2 = h[(n + 8) * 64 + lane];
    float a3 = h[(n + 12) * 64 + lane];
    acc += leakyf(fmaf(a0, sc, sh)) + leakyf(fmaf(a1, sc, sh))
         + leakyf(fmaf(a2, sc, sh)) + leakyf(fmaf(a3, sc, sh));
  }
  for (; n < end; n += 4)
    acc += leakyf(fmaf(h[n * 64 + lane], sc, sh));
  red[w][lane] = acc;
  __syncthreads();
  if (w == 0) {
    float tot = red[0][lane] + red[1][lane] + red[2][lane] + red[3][lane];
    out[g * 64 + lane] = tot / fmaxf((float)(end - start), 1.0f);
  }
}

extern "C" void kernel_launch(void* const* d_in, const int* in_sizes, int n_in,
                              void* d_out, int out_size, void* d_ws, size_t ws_size,
                              hipStream_t stream) {
  const float* x      = (const float*)d_in[0];
  const int*   eidx   = (const int*)d_in[1];
  const int*   batch  = (const int*)d_in[2];
  const float* eattr  = (const float*)d_in[3];
  const float* Wsrc   = (const float*)d_in[4];
  const float* bsrc   = (const float*)d_in[5];
  const float* Wdst   = (const float*)d_in[6];
  const float* bdst   = (const float*)d_in[7];
  const float* Wedge  = (const float*)d_in[8];
  const float* bedge  = (const float*)d_in[9];
  const float* tparam = (const float*)d_in[10];
  const float* W1     = (const float*)d_in[11];
  // d_in[12] = mlp_bias1 — cancels inside the following BatchNorm; skipped.
  const float* bng    = (const float*)d_in[13];
  const float* bnb    = (const float*)d_in[14];
  const float* W2     = (const float*)d_in[15];
  const float* b2     = (const float*)d_in[16];
  const float* ng     = (const float*)d_in[17];
  const float* nb     = (const float*)d_in[18];
  const int* srcp = eidx;              // edge_index[0]
  const int* dstp = eidx + N_EDGES;    // edge_index[1]

  char* ws = (char*)d_ws;
  size_t off = 0;
  auto alloc = [&](size_t bytes) {
    void* p = ws + off;
    off = (off + bytes + 255) & ~size_t(255);
    return p;
  };
  // ---- zero region (one memset) ----
  int*   counts   = (int*)alloc(N_NODES * 4);
  float* stats_y1 = (float*)alloc(L * 256 * 4);
  float* stats_h  = (float*)alloc(L * 128 * 4);
  size_t zero_bytes = off;
  // ---- rest ----
  int*   row_ptr    = (int*)alloc((N_NODES + 1) * 4);
  int*   cursor     = (int*)alloc(N_NODES * 4);
  int2*  edata      = (int2*)alloc(N_EDGES * 8);
  float* xs0        = (float*)alloc(N_NODES * 64 * 4);
  float* xd0        = (float*)alloc(N_NODES * 64 * 4);
  float* hbuf       = (float*)alloc(N_NODES * 64 * 4);
  float* y1         = (float*)alloc(N_NODES * 128 * 4);

  hipMemsetAsync(d_ws, 0, zero_bytes, stream);
  k_hist<<<(N_EDGES + 255) / 256, 256, 0, stream>>>(dstp, counts);
  k_scan<<<1, 1024, 0, stream>>>(counts, row_ptr, cursor, N_NODES);
  k_scatter<<<(N_EDGES + 255) / 256, 256, 0, stream>>>(srcp, dstp, eattr, cursor,
                                                       edata, N_EDGES);
  k_lin0<<<625, 256, 0, stream>>>(x, Wsrc, bsrc, Wdst, bdst, xs0, xd0);

  for (int i = 0; i < L; i++) {
    const float* xsp = (i == 0) ? xs0 : hbuf;
    const float* xdp = (i == 0) ? xd0 : hbuf;
    const float* nst = (i == 0) ? stats_h : stats_h + (i - 1) * 128;  // unused when use_bn=0
    k_conv<<<1250, 256, 0, stream>>>(xsp, xdp, nst, ng + i * 64, nb + i * 64, i > 0 ? 1 : 0,
                                     row_ptr, edata,
                                     Wedge + i * 64, bedge + i * 64, tparam + i,
                                     W1 + i * 64 * 128, y1, stats_y1 + i * 256);
    k_mlp2<<<1250, 256, 0, stream>>>(y1, stats_y1 + i * 256, bng + i * 128, bnb + i * 128,
                                     W2 + i * 128 * 64, b2 + i * 64, hbuf, i > 0 ? 1 : 0,
                                     stats_h + i * 128);
  }
  k_pool<<<N_GRAPHS, 256, 0, stream>>>(hbuf, stats_h + 7 * 128, ng, nb, batch, (float*)d_out);
}